// Round 8
// baseline (389.844 us; speedup 1.0000x reference)
//
#include <hip/hip_runtime.h>

#define DIM 128
#define NA 4096
#define NWORDS 16384
#define MAXNZ 256
#define KW 23
#define PAD 11

// ---------------- gather rows: out[i][:] = tab[idx[i]][:] (float4) ----------------
__global__ void k_gather(float* __restrict__ out, const float* __restrict__ tab,
                         const int* __restrict__ idx) {
  int t = blockIdx.x * blockDim.x + threadIdx.x;   // over n*32 float4s
  int r = t >> 5, c = t & 31;
  ((float4*)out)[t] = ((const float4*)(tab + (size_t)idx[r] * DIM))[c];
}

// ---------------- adjacency scan -> per-row (col,val) lists ----------------
__global__ void k_adj_scan(int* __restrict__ cnt, int* __restrict__ colx,
                           float* __restrict__ valx, const float* __restrict__ adj) {
  int w = threadIdx.x >> 6, lane = threadIdx.x & 63;
  int row = blockIdx.x * 4 + w;
  const float4* ar = (const float4*)(adj + (size_t)row * NA);
  int count = 0;
  unsigned long long ltm = (1ull << lane) - 1ull;
  for (int c4 = lane; c4 < NA / 4; c4 += 64) {
    float4 v = ar[c4];
    #pragma unroll
    for (int e = 0; e < 4; ++e) {
      float ve = e == 0 ? v.x : e == 1 ? v.y : e == 2 ? v.z : v.w;
      unsigned long long m = __ballot(ve != 0.0f);
      if (ve != 0.0f) {
        int off = count + (int)__popcll(m & ltm);
        if (off < MAXNZ) { colx[row * MAXNZ + off] = c4 * 4 + e; valx[row * MAXNZ + off] = ve; }
      }
      count += (int)__popcll(m);
    }
  }
  if (lane == 0) cnt[row] = count;
}

// ---------------- C[M,128] = relu(A[M,128] @ W[128,128]^T + b) ----------------
__global__ __launch_bounds__(256) void k_linear_relu(
    float* __restrict__ out, const float* __restrict__ A,
    const float* __restrict__ W, const float* __restrict__ bias) {
  __shared__ float As[64 * 132];
  __shared__ float Ws[64 * 132];
  int mt = blockIdx.x >> 1, nt = blockIdx.x & 1;
  int r0 = mt * 64, c0 = nt * 64;
  int tid = threadIdx.x;
  for (int q = tid; q < 64 * 32; q += 256) {
    int row = q >> 5, c4 = q & 31;
    *(float4*)&As[row * 132 + c4 * 4] = *(const float4*)&A[(size_t)(r0 + row) * DIM + c4 * 4];
    *(float4*)&Ws[row * 132 + c4 * 4] = *(const float4*)&W[(size_t)(c0 + row) * DIM + c4 * 4];
  }
  __syncthreads();
  int rgr = tid & 15, cgr = tid >> 4;
  float acc[4][4] = {};
  #pragma unroll 4
  for (int k4 = 0; k4 < 32; ++k4) {
    int kk = ((k4 + rgr) & 31) * 4;
    float4 a[4], w[4];
    #pragma unroll
    for (int i = 0; i < 4; ++i) a[i] = *(const float4*)&As[(rgr * 4 + i) * 132 + kk];
    #pragma unroll
    for (int j = 0; j < 4; ++j) w[j] = *(const float4*)&Ws[(cgr * 4 + j) * 132 + kk];
    #pragma unroll
    for (int i = 0; i < 4; ++i)
      #pragma unroll
      for (int j = 0; j < 4; ++j)
        acc[i][j] += a[i].x * w[j].x + a[i].y * w[j].y + a[i].z * w[j].z + a[i].w * w[j].w;
  }
  #pragma unroll
  for (int i = 0; i < 4; ++i) {
    int r = r0 + rgr * 4 + i;
    int c = c0 + cgr * 4;
    float4 bv = *(const float4*)&bias[c];
    float4 o;
    o.x = acc[i][0] + bv.x; o.y = acc[i][1] + bv.y;
    o.z = acc[i][2] + bv.z; o.w = acc[i][3] + bv.w;
    o.x = o.x > 0.f ? o.x : 0.f; o.y = o.y > 0.f ? o.y : 0.f;
    o.z = o.z > 0.f ? o.z : 0.f; o.w = o.w > 0.f ? o.w : 0.f;
    *(float4*)&out[(size_t)r * DIM + c] = o;
  }
}

// ---------------- xs[r][:] += sum_i val_i * hs[col_i][:] ----------------
__global__ void k_spmm(float* __restrict__ xs, const float* __restrict__ hs,
                       const int* __restrict__ cnt, const int* __restrict__ colx,
                       const float* __restrict__ valx, const float* __restrict__ adj) {
  __shared__ int scol[MAXNZ];
  __shared__ float sval[MAXNZ];
  int r = blockIdx.x, d = threadIdx.x;
  int n = cnt[r];
  int m = (n <= MAXNZ) ? n : 0;
  for (int i = d; i < m; i += 128) {
    scol[i] = colx[r * MAXNZ + i];
    sval[i] = valx[r * MAXNZ + i];
  }
  __syncthreads();
  float acc = xs[(size_t)r * DIM + d];
  if (n <= MAXNZ) {
    for (int i = 0; i < n; ++i)
      acc += sval[i] * hs[(size_t)scol[i] * DIM + d];
  } else {              // safety fallback, statistically never taken
    for (int c = 0; c < NA; ++c) {
      float a = adj[(size_t)r * NA + c];
      if (a != 0.f) acc += a * hs[(size_t)c * DIM + d];
    }
  }
  xs[(size_t)r * DIM + d] = acc;
}

// ---------------- column mean (scaled), atomic partials ----------------
__global__ void k_mean(float* __restrict__ out, const float* __restrict__ in,
                       int rows_per_block, float scale) {
  __shared__ float red[256];
  int d = threadIdx.x & 127, half = threadIdx.x >> 7;
  int r0 = blockIdx.x * rows_per_block;
  float acc = 0.f;
  for (int r = r0 + half; r < r0 + rows_per_block; r += 2)
    acc += in[(size_t)r * DIM + d];
  red[threadIdx.x] = acc;
  __syncthreads();
  if (half == 0) atomicAdd(&out[d], (acc + red[threadIdx.x + 128]) * scale);
}

// ---------------- 23x23 conv (1 channel) + bias + leaky relu ----------------
// TRANSPOSED tile [col][row], row stride 44 dwords: the per-dx 30-row window
// is contiguous -> 8x ds_read_b128 (vs 30x b32). Lane stride 44 dwords = 12
// banks (gcd 4 with 32): 16-lane phases hit each bank exactly 2x = free.
// __launch_bounds__(256,4): VGPR budget 128 so the window+acc stay in regs
// (round-7 counter evidence: VGPR=36 -> compiler rematerialized LDS reads).
#define CROWS 16
#define TROWS 38      // CROWS + 22
#define TCOLS 150     // DIM + 22
#define TSTRT 44      // dwords; multiple of 4 (16B alignment), 12-bank step
__global__ __launch_bounds__(256, 4) void k_conv(
    float* __restrict__ out, const float* __restrict__ in,
    const float* __restrict__ cw, const float* __restrict__ cb) {
  __shared__ float tileT[TCOLS * TSTRT];   // [col][row], 26.4 KB
  int r0 = blockIdx.x * CROWS;
  int tid = threadIdx.x;
  for (int p = tid; p < TROWS * TCOLS; p += 256) {
    int rr = p / TCOLS, cc = p - rr * TCOLS;
    int gr = r0 - PAD + rr, gc = cc - PAD;
    float v = 0.f;
    if ((unsigned)gr < NWORDS && (unsigned)gc < DIM) v = in[(size_t)gr * DIM + gc];
    tileT[cc * TSTRT + rr] = v;
  }
  __syncthreads();
  int col = tid & 127, rb = tid >> 7;      // rb in {0,1}
  int rbase = rb * 8;                      // 8 output rows per thread
  float acc[8] = {};
  for (int dx = 0; dx < KW; ++dx) {
    const float* src = &tileT[(col + dx) * TSTRT + rbase];
    float4 v4[8];
    #pragma unroll
    for (int q = 0; q < 8; ++q) v4[q] = *(const float4*)&src[q * 4];
    const float* v = (const float*)v4;     // v[0..31], rows rbase..rbase+31
    const float* wp = cw + dx;             // wave-uniform -> s_loads
    #pragma unroll
    for (int dy = 0; dy < KW; ++dy) {
      float wv = wp[dy * KW];
      #pragma unroll
      for (int i = 0; i < 8; ++i) acc[i] += wv * v[i + dy];
    }
  }
  float bias = cb[0];
  #pragma unroll
  for (int i = 0; i < 8; ++i) {
    float x = acc[i] + bias;
    out[(size_t)(r0 + rbase + i) * DIM + col] = x > 0.f ? x : 0.01f * x;
  }
}

// ---------------- fused: h = relu(W comp + b); attw = tanh(h.hsA[r]); prot += attw*hsA/N ----------------
__global__ __launch_bounds__(256) void k_attprot(
    float* __restrict__ prot, const float* __restrict__ hsA,
    const float* __restrict__ comp, const float* __restrict__ W,
    const float* __restrict__ b) {
  __shared__ float cvec[DIM];
  __shared__ float hv_s[DIM];
  __shared__ float lw[32];
  __shared__ float red[256];
  int tid = threadIdx.x;
  int w = tid >> 6, lane = tid & 63;
  if (tid < 128) cvec[tid] = comp[tid];
  __syncthreads();
  if (tid < 128) {
    float acc = b[tid];
    #pragma unroll
    for (int k4 = 0; k4 < 32; ++k4) {
      float4 w4 = *(const float4*)&W[tid * DIM + k4 * 4];
      acc += cvec[k4*4+0] * w4.x + cvec[k4*4+1] * w4.y + cvec[k4*4+2] * w4.z + cvec[k4*4+3] * w4.w;
    }
    hv_s[tid] = acc > 0.f ? acc : 0.f;
  }
  __syncthreads();
  int r0 = blockIdx.x * 32;
  float2 hv = ((const float2*)hv_s)[lane];
  for (int rr = w; rr < 32; rr += 4) {
    float2 xv = ((const float2*)(hsA + (size_t)(r0 + rr) * DIM))[lane];
    float dt = hv.x * xv.x + hv.y * xv.y;
    for (int o = 32; o > 0; o >>= 1) dt += __shfl_xor(dt, o);
    if (lane == 0) lw[rr] = tanhf(dt);
  }
  __syncthreads();
  int d = tid & 127, half = tid >> 7;
  float acc = 0.f;
  for (int rr = half; rr < 32; rr += 2)
    acc += lw[rr] * hsA[(size_t)(r0 + rr) * DIM + d];
  red[tid] = acc;
  __syncthreads();
  if (half == 0) atomicAdd(&prot[d], (acc + red[tid + 128]) * (1.f / NWORDS));
}

// ---------------- output MLP: cat(256) -> 2x relu-linear(256) -> scalar ----------------
__global__ __launch_bounds__(256) void k_final(
    float* __restrict__ out, const float* __restrict__ comp, const float* __restrict__ prot,
    const float* __restrict__ Wo, const float* __restrict__ bo,
    const float* __restrict__ Wi, const float* __restrict__ bi) {
  __shared__ float cat[256];
  __shared__ float wred[4];
  int t = threadIdx.x;
  int w = t >> 6, lane = t & 63;
  cat[t] = t < 128 ? comp[t] : prot[t - 128];
  __syncthreads();
  for (int l = 0; l < 2; ++l) {
    const float* Wl = Wo + l * 256 * 256;
    float acc = bo[l * 256 + t];
    #pragma unroll 8
    for (int k4 = 0; k4 < 64; ++k4) {
      float4 w4 = *(const float4*)&Wl[t * 256 + k4 * 4];
      acc += cat[k4*4+0] * w4.x + cat[k4*4+1] * w4.y + cat[k4*4+2] * w4.z + cat[k4*4+3] * w4.w;
    }
    __syncthreads();
    cat[t] = acc > 0.f ? acc : 0.f;
    __syncthreads();
  }
  float r = cat[t] * Wi[t];
  for (int o = 32; o > 0; o >>= 1) r += __shfl_xor(r, o);
  if (lane == 0) wred[w] = r;
  __syncthreads();
  if (t == 0) out[0] = wred[0] + wred[1] + wred[2] + wred[3] + bi[0];
}

extern "C" void kernel_launch(void* const* d_in, const int* in_sizes, int n_in,
                              void* d_out, int out_size, void* d_ws, size_t ws_size,
                              hipStream_t stream) {
  const int*   fingerprints = (const int*)d_in[0];
  const float* adjacency    = (const float*)d_in[1];
  const int*   words        = (const int*)d_in[2];
  const float* emb_fp       = (const float*)d_in[3];
  const float* emb_word     = (const float*)d_in[4];
  const float* W_gnn_w      = (const float*)d_in[5];
  const float* W_gnn_b      = (const float*)d_in[6];
  const float* conv_w       = (const float*)d_in[7];
  const float* conv_b       = (const float*)d_in[8];
  const float* W_att_w      = (const float*)d_in[9];
  const float* W_att_b      = (const float*)d_in[10];
  const float* W_out_w      = (const float*)d_in[11];
  const float* W_out_b      = (const float*)d_in[12];
  const float* W_int_w      = (const float*)d_in[13];
  const float* W_int_b      = (const float*)d_in[14];
  float* out = (float*)d_out;

  float* xs   = (float*)d_ws;               // 524288
  float* hsb  = xs   + 524288;              // 524288
  float* valx = hsb  + 524288;              // 1048576
  float* pa   = valx + 1048576;             // 2097152
  float* pb   = pa   + 2097152;             // 2097152
  float* hsA  = pb   + 2097152;             // 2097152
  float* attw = hsA  + 2097152;             // 16384
  float* small= attw + 16384;               // 512
  int*   colx = (int*)(small + 512);        // 1048576
  int*   cntv = colx + 1048576;             // 4096
  float* comp = small, *prot = small + 128;
  (void)attw;

  hipMemsetAsync(small, 0, 512 * sizeof(float), stream);

  // ---- GNN ----
  k_gather<<<512, 256, 0, stream>>>(xs, emb_fp, fingerprints);
  k_adj_scan<<<1024, 256, 0, stream>>>(cntv, colx, valx, adjacency);
  for (int l = 0; l < 3; ++l) {
    k_linear_relu<<<128, 256, 0, stream>>>(hsb, xs, W_gnn_w + l * DIM * DIM, W_gnn_b + l * DIM);
    k_spmm<<<NA, 128, 0, stream>>>(xs, hsb, cntv, colx, valx, adjacency);
  }
  k_mean<<<128, 256, 0, stream>>>(comp, xs, 32, 1.0f / NA);

  // ---- protein CNN ----
  k_gather<<<2048, 256, 0, stream>>>(pa, emb_word, words);
  k_conv<<<1024, 256, 0, stream>>>(pb, pa, conv_w + 0 * 529, conv_b + 0);
  k_conv<<<1024, 256, 0, stream>>>(pa, pb, conv_w + 1 * 529, conv_b + 1);
  k_conv<<<1024, 256, 0, stream>>>(pb, pa, conv_w + 2 * 529, conv_b + 2);

  // ---- attention ----
  k_linear_relu<<<512, 256, 0, stream>>>(hsA, pb, W_att_w, W_att_b);
  k_attprot<<<512, 256, 0, stream>>>(prot, hsA, comp, W_att_w, W_att_b);

  // ---- output MLP ----
  k_final<<<1, 256, 0, stream>>>(out, comp, prot, W_out_w, W_out_b, W_int_w, W_int_b);
}

// Round 9
// 370.699 us; speedup vs baseline: 1.0516x; 1.0516x over previous
//
#include <hip/hip_runtime.h>

#define DIM 128
#define NA 4096
#define NWORDS 16384
#define MAXNZ 256
#define KW 23
#define PAD 11

// ---------------- gather rows: out[i][:] = tab[idx[i]][:] (float4) ----------------
__global__ void k_gather(float* __restrict__ out, const float* __restrict__ tab,
                         const int* __restrict__ idx) {
  int t = blockIdx.x * blockDim.x + threadIdx.x;   // over n*32 float4s
  int r = t >> 5, c = t & 31;
  ((float4*)out)[t] = ((const float4*)(tab + (size_t)idx[r] * DIM))[c];
}

// ---------------- adjacency scan -> per-row (col,val) lists ----------------
__global__ void k_adj_scan(int* __restrict__ cnt, int* __restrict__ colx,
                           float* __restrict__ valx, const float* __restrict__ adj) {
  int w = threadIdx.x >> 6, lane = threadIdx.x & 63;
  int row = blockIdx.x * 4 + w;
  const float4* ar = (const float4*)(adj + (size_t)row * NA);
  int count = 0;
  unsigned long long ltm = (1ull << lane) - 1ull;
  for (int c4 = lane; c4 < NA / 4; c4 += 64) {
    float4 v = ar[c4];
    #pragma unroll
    for (int e = 0; e < 4; ++e) {
      float ve = e == 0 ? v.x : e == 1 ? v.y : e == 2 ? v.z : v.w;
      unsigned long long m = __ballot(ve != 0.0f);
      if (ve != 0.0f) {
        int off = count + (int)__popcll(m & ltm);
        if (off < MAXNZ) { colx[row * MAXNZ + off] = c4 * 4 + e; valx[row * MAXNZ + off] = ve; }
      }
      count += (int)__popcll(m);
    }
  }
  if (lane == 0) cnt[row] = count;
}

// ---------------- C[M,128] = relu(A[M,128] @ W[128,128]^T + b) ----------------
__global__ __launch_bounds__(256) void k_linear_relu(
    float* __restrict__ out, const float* __restrict__ A,
    const float* __restrict__ W, const float* __restrict__ bias) {
  __shared__ float As[64 * 132];
  __shared__ float Ws[64 * 132];
  int mt = blockIdx.x >> 1, nt = blockIdx.x & 1;
  int r0 = mt * 64, c0 = nt * 64;
  int tid = threadIdx.x;
  for (int q = tid; q < 64 * 32; q += 256) {
    int row = q >> 5, c4 = q & 31;
    *(float4*)&As[row * 132 + c4 * 4] = *(const float4*)&A[(size_t)(r0 + row) * DIM + c4 * 4];
    *(float4*)&Ws[row * 132 + c4 * 4] = *(const float4*)&W[(size_t)(c0 + row) * DIM + c4 * 4];
  }
  __syncthreads();
  int rgr = tid & 15, cgr = tid >> 4;
  float acc[4][4] = {};
  #pragma unroll 4
  for (int k4 = 0; k4 < 32; ++k4) {
    int kk = ((k4 + rgr) & 31) * 4;
    float4 a[4], w[4];
    #pragma unroll
    for (int i = 0; i < 4; ++i) a[i] = *(const float4*)&As[(rgr * 4 + i) * 132 + kk];
    #pragma unroll
    for (int j = 0; j < 4; ++j) w[j] = *(const float4*)&Ws[(cgr * 4 + j) * 132 + kk];
    #pragma unroll
    for (int i = 0; i < 4; ++i)
      #pragma unroll
      for (int j = 0; j < 4; ++j)
        acc[i][j] += a[i].x * w[j].x + a[i].y * w[j].y + a[i].z * w[j].z + a[i].w * w[j].w;
  }
  #pragma unroll
  for (int i = 0; i < 4; ++i) {
    int r = r0 + rgr * 4 + i;
    int c = c0 + cgr * 4;
    float4 bv = *(const float4*)&bias[c];
    float4 o;
    o.x = acc[i][0] + bv.x; o.y = acc[i][1] + bv.y;
    o.z = acc[i][2] + bv.z; o.w = acc[i][3] + bv.w;
    o.x = o.x > 0.f ? o.x : 0.f; o.y = o.y > 0.f ? o.y : 0.f;
    o.z = o.z > 0.f ? o.z : 0.f; o.w = o.w > 0.f ? o.w : 0.f;
    *(float4*)&out[(size_t)r * DIM + c] = o;
  }
}

// ---------------- xs[r][:] += sum_i val_i * hs[col_i][:] ----------------
__global__ void k_spmm(float* __restrict__ xs, const float* __restrict__ hs,
                       const int* __restrict__ cnt, const int* __restrict__ colx,
                       const float* __restrict__ valx, const float* __restrict__ adj) {
  __shared__ int scol[MAXNZ];
  __shared__ float sval[MAXNZ];
  int r = blockIdx.x, d = threadIdx.x;
  int n = cnt[r];
  int m = (n <= MAXNZ) ? n : 0;
  for (int i = d; i < m; i += 128) {
    scol[i] = colx[r * MAXNZ + i];
    sval[i] = valx[r * MAXNZ + i];
  }
  __syncthreads();
  float acc = xs[(size_t)r * DIM + d];
  if (n <= MAXNZ) {
    for (int i = 0; i < n; ++i)
      acc += sval[i] * hs[(size_t)scol[i] * DIM + d];
  } else {              // safety fallback, statistically never taken
    for (int c = 0; c < NA; ++c) {
      float a = adj[(size_t)r * NA + c];
      if (a != 0.f) acc += a * hs[(size_t)c * DIM + d];
    }
  }
  xs[(size_t)r * DIM + d] = acc;
}

// ---------------- column mean (scaled), atomic partials ----------------
__global__ void k_mean(float* __restrict__ out, const float* __restrict__ in,
                       int rows_per_block, float scale) {
  __shared__ float red[256];
  int d = threadIdx.x & 127, half = threadIdx.x >> 7;
  int r0 = blockIdx.x * rows_per_block;
  float acc = 0.f;
  for (int r = r0 + half; r < r0 + rows_per_block; r += 2)
    acc += in[(size_t)r * DIM + d];
  red[threadIdx.x] = acc;
  __syncthreads();
  if (half == 0) atomicAdd(&out[d], (acc + red[threadIdx.x + 128]) * scale);
}

// ---------------- 23x23 conv (1 channel) + bias + leaky relu ----------------
// Row-major tile, column-per-thread (lane-stride-1 b32 = conflict-free under
// the calibrated 32-lane/phase bank model; rounds 5/7 measured 0 conflicts).
// ROLLING 8-register window over dy: preload 8, then each dy-step = 8 FMA +
// 1 replacement load into the just-freed slot R[(dy)&7]. All R[]/acc[] indices
// are literals -> guaranteed VGPR residency (rounds 5-8: VGPR=36..48 + scratch
// FETCH proved the 30-float window was being rematerialized/spilled).
#define CROWS 16
#define TROWS 38      // CROWS + 22
#define TCOLS 150     // DIM + 22
#define TSTR  150
__global__ __launch_bounds__(256, 4) void k_conv(
    float* __restrict__ out, const float* __restrict__ in,
    const float* __restrict__ cw, const float* __restrict__ cb) {
  __shared__ float tile[TROWS * TSTR];
  int r0 = blockIdx.x * CROWS;
  int tid = threadIdx.x;
  for (int p = tid; p < TROWS * TCOLS; p += 256) {
    int rr = p / TCOLS, cc = p - rr * TCOLS;
    int gr = r0 - PAD + rr, gc = cc - PAD;
    float v = 0.f;
    if ((unsigned)gr < NWORDS && (unsigned)gc < DIM) v = in[(size_t)gr * DIM + gc];
    tile[rr * TSTR + cc] = v;
  }
  __syncthreads();
  int col = tid & 127, rb = tid >> 7;      // rb in {0,1}
  int rbase = rb * 8;                      // 8 output rows per thread
  float acc[8] = {};
  const float* base0 = &tile[rbase * TSTR + col];
  for (int dx = 0; dx < KW; ++dx) {
    const float* base = base0 + dx;
    const float* wp = cw + dx;             // wave-uniform -> s_loads
    float R[8];
    R[0] = base[0 * TSTR]; R[1] = base[1 * TSTR];
    R[2] = base[2 * TSTR]; R[3] = base[3 * TSTR];
    R[4] = base[4 * TSTR]; R[5] = base[5 * TSTR];
    R[6] = base[6 * TSTR]; R[7] = base[7 * TSTR];
#define CSTEP(dy) { \
    float wv = wp[(dy) * KW]; \
    acc[0] += wv * R[((dy) + 0) & 7]; \
    acc[1] += wv * R[((dy) + 1) & 7]; \
    acc[2] += wv * R[((dy) + 2) & 7]; \
    acc[3] += wv * R[((dy) + 3) & 7]; \
    acc[4] += wv * R[((dy) + 4) & 7]; \
    acc[5] += wv * R[((dy) + 5) & 7]; \
    acc[6] += wv * R[((dy) + 6) & 7]; \
    acc[7] += wv * R[((dy) + 7) & 7]; \
    if ((dy) < 22) R[(dy) & 7] = base[((dy) + 8) * TSTR]; }
    CSTEP(0)  CSTEP(1)  CSTEP(2)  CSTEP(3)  CSTEP(4)  CSTEP(5)
    CSTEP(6)  CSTEP(7)  CSTEP(8)  CSTEP(9)  CSTEP(10) CSTEP(11)
    CSTEP(12) CSTEP(13) CSTEP(14) CSTEP(15) CSTEP(16) CSTEP(17)
    CSTEP(18) CSTEP(19) CSTEP(20) CSTEP(21) CSTEP(22)
#undef CSTEP
  }
  float bias = cb[0];
  #pragma unroll
  for (int i = 0; i < 8; ++i) {
    float x = acc[i] + bias;
    out[(size_t)(r0 + rbase + i) * DIM + col] = x > 0.f ? x : 0.01f * x;
  }
}

// ---------------- fused: h = relu(W comp + b); attw = tanh(h.hsA[r]); prot += attw*hsA/N ----------------
__global__ __launch_bounds__(256) void k_attprot(
    float* __restrict__ prot, const float* __restrict__ hsA,
    const float* __restrict__ comp, const float* __restrict__ W,
    const float* __restrict__ b) {
  __shared__ float cvec[DIM];
  __shared__ float hv_s[DIM];
  __shared__ float lw[32];
  __shared__ float red[256];
  int tid = threadIdx.x;
  int w = tid >> 6, lane = tid & 63;
  if (tid < 128) cvec[tid] = comp[tid];
  __syncthreads();
  if (tid < 128) {
    float acc = b[tid];
    #pragma unroll
    for (int k4 = 0; k4 < 32; ++k4) {
      float4 w4 = *(const float4*)&W[tid * DIM + k4 * 4];
      acc += cvec[k4*4+0] * w4.x + cvec[k4*4+1] * w4.y + cvec[k4*4+2] * w4.z + cvec[k4*4+3] * w4.w;
    }
    hv_s[tid] = acc > 0.f ? acc : 0.f;
  }
  __syncthreads();
  int r0 = blockIdx.x * 32;
  float2 hv = ((const float2*)hv_s)[lane];
  for (int rr = w; rr < 32; rr += 4) {
    float2 xv = ((const float2*)(hsA + (size_t)(r0 + rr) * DIM))[lane];
    float dt = hv.x * xv.x + hv.y * xv.y;
    for (int o = 32; o > 0; o >>= 1) dt += __shfl_xor(dt, o);
    if (lane == 0) lw[rr] = tanhf(dt);
  }
  __syncthreads();
  int d = tid & 127, half = tid >> 7;
  float acc = 0.f;
  for (int rr = half; rr < 32; rr += 2)
    acc += lw[rr] * hsA[(size_t)(r0 + rr) * DIM + d];
  red[tid] = acc;
  __syncthreads();
  if (half == 0) atomicAdd(&prot[d], (acc + red[tid + 128]) * (1.f / NWORDS));
}

// ---------------- output MLP: cat(256) -> 2x relu-linear(256) -> scalar ----------------
__global__ __launch_bounds__(256) void k_final(
    float* __restrict__ out, const float* __restrict__ comp, const float* __restrict__ prot,
    const float* __restrict__ Wo, const float* __restrict__ bo,
    const float* __restrict__ Wi, const float* __restrict__ bi) {
  __shared__ float cat[256];
  __shared__ float wred[4];
  int t = threadIdx.x;
  int w = t >> 6, lane = t & 63;
  cat[t] = t < 128 ? comp[t] : prot[t - 128];
  __syncthreads();
  for (int l = 0; l < 2; ++l) {
    const float* Wl = Wo + l * 256 * 256;
    float acc = bo[l * 256 + t];
    #pragma unroll 8
    for (int k4 = 0; k4 < 64; ++k4) {
      float4 w4 = *(const float4*)&Wl[t * 256 + k4 * 4];
      acc += cat[k4*4+0] * w4.x + cat[k4*4+1] * w4.y + cat[k4*4+2] * w4.z + cat[k4*4+3] * w4.w;
    }
    __syncthreads();
    cat[t] = acc > 0.f ? acc : 0.f;
    __syncthreads();
  }
  float r = cat[t] * Wi[t];
  for (int o = 32; o > 0; o >>= 1) r += __shfl_xor(r, o);
  if (lane == 0) wred[w] = r;
  __syncthreads();
  if (t == 0) out[0] = wred[0] + wred[1] + wred[2] + wred[3] + bi[0];
}

extern "C" void kernel_launch(void* const* d_in, const int* in_sizes, int n_in,
                              void* d_out, int out_size, void* d_ws, size_t ws_size,
                              hipStream_t stream) {
  const int*   fingerprints = (const int*)d_in[0];
  const float* adjacency    = (const float*)d_in[1];
  const int*   words        = (const int*)d_in[2];
  const float* emb_fp       = (const float*)d_in[3];
  const float* emb_word     = (const float*)d_in[4];
  const float* W_gnn_w      = (const float*)d_in[5];
  const float* W_gnn_b      = (const float*)d_in[6];
  const float* conv_w       = (const float*)d_in[7];
  const float* conv_b       = (const float*)d_in[8];
  const float* W_att_w      = (const float*)d_in[9];
  const float* W_att_b      = (const float*)d_in[10];
  const float* W_out_w      = (const float*)d_in[11];
  const float* W_out_b      = (const float*)d_in[12];
  const float* W_int_w      = (const float*)d_in[13];
  const float* W_int_b      = (const float*)d_in[14];
  float* out = (float*)d_out;

  float* xs   = (float*)d_ws;               // 524288
  float* hsb  = xs   + 524288;              // 524288
  float* valx = hsb  + 524288;              // 1048576
  float* pa   = valx + 1048576;             // 2097152
  float* pb   = pa   + 2097152;             // 2097152
  float* hsA  = pb   + 2097152;             // 2097152
  float* attw = hsA  + 2097152;             // 16384
  float* small= attw + 16384;               // 512
  int*   colx = (int*)(small + 512);        // 1048576
  int*   cntv = colx + 1048576;             // 4096
  float* comp = small, *prot = small + 128;
  (void)attw;

  hipMemsetAsync(small, 0, 512 * sizeof(float), stream);

  // ---- GNN ----
  k_gather<<<512, 256, 0, stream>>>(xs, emb_fp, fingerprints);
  k_adj_scan<<<1024, 256, 0, stream>>>(cntv, colx, valx, adjacency);
  for (int l = 0; l < 3; ++l) {
    k_linear_relu<<<128, 256, 0, stream>>>(hsb, xs, W_gnn_w + l * DIM * DIM, W_gnn_b + l * DIM);
    k_spmm<<<NA, 128, 0, stream>>>(xs, hsb, cntv, colx, valx, adjacency);
  }
  k_mean<<<128, 256, 0, stream>>>(comp, xs, 32, 1.0f / NA);

  // ---- protein CNN ----
  k_gather<<<2048, 256, 0, stream>>>(pa, emb_word, words);
  k_conv<<<1024, 256, 0, stream>>>(pb, pa, conv_w + 0 * 529, conv_b + 0);
  k_conv<<<1024, 256, 0, stream>>>(pa, pb, conv_w + 1 * 529, conv_b + 1);
  k_conv<<<1024, 256, 0, stream>>>(pb, pa, conv_w + 2 * 529, conv_b + 2);

  // ---- attention ----
  k_linear_relu<<<512, 256, 0, stream>>>(hsA, pb, W_att_w, W_att_b);
  k_attprot<<<512, 256, 0, stream>>>(prot, hsA, comp, W_att_w, W_att_b);

  // ---- output MLP ----
  k_final<<<1, 256, 0, stream>>>(out, comp, prot, W_out_w, W_out_b, W_int_w, W_int_b);
}